// Round 7
// baseline (712.378 us; speedup 1.0000x reference)
//
#include <hip/hip_runtime.h>
#include <hip/hip_bf16.h>
#include <math.h>

#define N_NODES 50000
#define N_EDGES 200000
#define N_REL   4
#define FDIM    128

typedef __attribute__((ext_vector_type(8))) short short8;
typedef __attribute__((ext_vector_type(4))) float f32x4;

static __device__ __forceinline__ ushort f2bf(float f) {
  union { float f; unsigned u; } v; v.f = f;
  unsigned r = v.u + 0x7fff + ((v.u >> 16) & 1);   // RNE
  return (ushort)(r >> 16);
}
// packed f32 pair -> bf16x2 (v_cvt_pk_bf16_f32 via compiler)
static __device__ __forceinline__ unsigned pk2(float lo, float hi) {
  __hip_bfloat162 t = __float22bfloat162_rn(make_float2(lo, hi));
  union { __hip_bfloat162 b; unsigned u; } v; v.b = t;
  return v.u;
}
static __device__ __forceinline__ float lo2f(unsigned u) {
  union { unsigned u; float f; } v; v.u = u << 16; return v.f;
}
static __device__ __forceinline__ float hi2f(unsigned u) {
  union { unsigned u; float f; } v; v.u = u & 0xffff0000u; return v.f;
}

// ---------- CSR build: counts ----------
__global__ void cnt_kernel(const int* __restrict__ dst, int* __restrict__ cnt) {
  int i = blockIdx.x * 256 + threadIdx.x;
  if (i < N_REL * N_EDGES) {
    int r = i / N_EDGES;
    atomicAdd(&cnt[r * N_NODES + dst[i]], 1);
  }
}

// ---------- per-relation exclusive scan (+ norm fold) ----------
__global__ void scan_kernel(const int* __restrict__ cnt, int* __restrict__ row,
                            int* __restrict__ cursor, float* __restrict__ nrm) {
  int r = blockIdx.x;
  int t = threadIdx.x;
  const int CH = (N_NODES + 1023) / 1024;
  int s = t * CH, e2 = min(s + CH, N_NODES);
  int sum = 0;
  for (int n = s; n < e2; ++n) {
    int c = cnt[r * N_NODES + n];
    nrm[r * N_NODES + n] = c > 0 ? 1.f / (float)c : 0.f;
    row[r * N_NODES + n] = sum; sum += c;
  }
  __shared__ int ts[1024];
  ts[t] = sum;
  __syncthreads();
  for (int off = 1; off < 1024; off <<= 1) {
    int v = 0;
    if (t >= off) v = ts[t - off];
    __syncthreads();
    ts[t] += v;
    __syncthreads();
  }
  int prefix = (t > 0 ? ts[t - 1] : 0) + r * N_EDGES;
  for (int n = s; n < e2; ++n) {
    int v = row[r * N_NODES + n] + prefix;
    row[r * N_NODES + n] = v;
    cursor[r * N_NODES + n] = v;
  }
}

// ---------- CSR fill ----------
__global__ void fill_kernel(const int* __restrict__ src, const int* __restrict__ dst,
                            int* __restrict__ cursor, int* __restrict__ csr_s) {
  int i = blockIdx.x * 256 + threadIdx.x;
  if (i < N_REL * N_EDGES) {
    int r = i / N_EDGES;
    int pos = atomicAdd(&cursor[r * N_NODES + dst[i]], 1);
    csr_s[pos] = src[i];
  }
}

// ---------- merged prep: cast x->bf16, P1w^T, W1^T, W2^T ----------
__global__ void prep_all_kernel(const float* __restrict__ x, ushort* __restrict__ xb,
                                const float* __restrict__ P1w, ushort* __restrict__ bT,
                                const float* __restrict__ W1, ushort* __restrict__ wT1,
                                const float* __restrict__ W2, ushort* __restrict__ wT2) {
  const int NC = N_NODES * FDIM / 4;          // 1.6M float4 casts
  int i = blockIdx.x * 256 + threadIdx.x;
  if (i < NC) {
    float4 v = ((const float4*)x)[i];
    ((uint2*)xb)[i] = make_uint2(pk2(v.x, v.y), pk2(v.z, v.w));
    return;
  }
  int i2 = i - NC;
  if (i2 < FDIM * FDIM) {                      // bT[c][k] = P1w[k][c]
    int c = i2 >> 7, k = i2 & 127;
    bT[i2] = f2bf(P1w[k * FDIM + c]);
    return;
  }
  i2 -= FDIM * FDIM;
  if (i2 < N_REL * FDIM * FDIM) {              // wT1[r][c][k] = W1[r][k][c]
    int r = i2 >> 14, c = (i2 >> 7) & 127, k = i2 & 127;
    wT1[i2] = f2bf(W1[(r << 14) + (k << 7) + c]);
    return;
  }
  i2 -= N_REL * FDIM * FDIM;
  if (i2 < N_REL * FDIM * FDIM) {
    int r = i2 >> 14, c = (i2 >> 7) & 127, k = i2 & 127;
    wT2[i2] = f2bf(W2[(r << 14) + (k << 7) + c]);
  }
}

// ---------- fused conv: MLP-4 register gather + bf16 MFMA over 4 relations ----------
__global__ __launch_bounds__(256) void conv_mfma_kernel(
    const ushort* __restrict__ hin, const int* __restrict__ rowp,
    const int* __restrict__ cnt, const float* __restrict__ nrm,
    const int* __restrict__ csr_s, const ushort* __restrict__ wT,
    const float* __restrict__ bias, ushort* __restrict__ hout, int do_relu) {
  __shared__ __align__(16) short elds[64 * 128];   // bf16 agg tile, XOR-swizzled
  __shared__ float nrm_lds[64];
  int tid  = threadIdx.x;
  int wave = tid >> 6, lane = tid & 63;
  int base = blockIdx.x * 64;
  int ig = tid >> 4, l16 = tid & 15;   // 16 gather groups × 16 lanes

  float tot[4][2][4];
#pragma unroll
  for (int tr = 0; tr < 4; ++tr)
#pragma unroll
    for (int t2 = 0; t2 < 2; ++t2)
#pragma unroll
      for (int j2 = 0; j2 < 4; ++j2) tot[tr][t2][j2] = 0.f;

  for (int r = 0; r < N_REL; ++r) {
    if (r > 0) __syncthreads();   // previous MFMA readers done before restaging
    if (tid < 64) {
      int n = base + tid;
      nrm_lds[tid] = (n < N_NODES) ? nrm[r * N_NODES + n] : 0.f;
    }

    // gather: group ig owns rows {ig, ig+16, ig+32, ig+48}; MLP-4 edge unroll
    for (int rr = ig; rr < 64; rr += 16) {
      int n = base + rr;
      float a8[8];
#pragma unroll
      for (int q = 0; q < 8; ++q) a8[q] = 0.f;
      if (n < N_NODES) {
        int idx = r * N_NODES + n;
        int beg = rowp[idx], num = cnt[idx];
        int j = 0;
        for (; j + 4 <= num; j += 4) {
          int s0 = csr_s[beg + j], s1 = csr_s[beg + j + 1];
          int s2 = csr_s[beg + j + 2], s3 = csr_s[beg + j + 3];
          uint4 v0 = *(const uint4*)(hin + (size_t)s0 * FDIM + l16 * 8);
          uint4 v1 = *(const uint4*)(hin + (size_t)s1 * FDIM + l16 * 8);
          uint4 v2 = *(const uint4*)(hin + (size_t)s2 * FDIM + l16 * 8);
          uint4 v3 = *(const uint4*)(hin + (size_t)s3 * FDIM + l16 * 8);
#pragma unroll
          for (int q = 0; q < 1; ++q) { /* keep scope */ }
          a8[0] += lo2f(v0.x) + lo2f(v1.x) + lo2f(v2.x) + lo2f(v3.x);
          a8[1] += hi2f(v0.x) + hi2f(v1.x) + hi2f(v2.x) + hi2f(v3.x);
          a8[2] += lo2f(v0.y) + lo2f(v1.y) + lo2f(v2.y) + lo2f(v3.y);
          a8[3] += hi2f(v0.y) + hi2f(v1.y) + hi2f(v2.y) + hi2f(v3.y);
          a8[4] += lo2f(v0.z) + lo2f(v1.z) + lo2f(v2.z) + lo2f(v3.z);
          a8[5] += hi2f(v0.z) + hi2f(v1.z) + hi2f(v2.z) + hi2f(v3.z);
          a8[6] += lo2f(v0.w) + lo2f(v1.w) + lo2f(v2.w) + lo2f(v3.w);
          a8[7] += hi2f(v0.w) + hi2f(v1.w) + hi2f(v2.w) + hi2f(v3.w);
        }
        for (; j < num; ++j) {
          int s = csr_s[beg + j];
          uint4 v = *(const uint4*)(hin + (size_t)s * FDIM + l16 * 8);
          a8[0] += lo2f(v.x); a8[1] += hi2f(v.x);
          a8[2] += lo2f(v.y); a8[3] += hi2f(v.y);
          a8[4] += lo2f(v.z); a8[5] += hi2f(v.z);
          a8[6] += lo2f(v.w); a8[7] += hi2f(v.w);
        }
      }
      int byte = rr * 256 + l16 * 16;
      byte ^= (rr & 7) << 4;
      *(uint4*)((char*)elds + byte) =
          make_uint4(pk2(a8[0], a8[1]), pk2(a8[2], a8[3]),
                     pk2(a8[4], a8[5]), pk2(a8[6], a8[7]));
    }
    __syncthreads();

    // B fragments: wT[r][c][k], c = wave*32 + t2*16 + (lane&15)
    short8 bfrag[2][4];
#pragma unroll
    for (int t2 = 0; t2 < 2; ++t2) {
      int c = wave * 32 + t2 * 16 + (lane & 15);
#pragma unroll
      for (int k0 = 0; k0 < 4; ++k0)
        bfrag[t2][k0] = *(const short8*)(wT + ((size_t)r * FDIM + c) * FDIM + k0 * 32 + (lane >> 4) * 8);
    }

#pragma unroll
    for (int tr = 0; tr < 4; ++tr) {
      int arow = tr * 16 + (lane & 15);
      short8 afrag[4];
#pragma unroll
      for (int k0 = 0; k0 < 4; ++k0) {
        int byte = arow * 256 + k0 * 64 + (lane >> 4) * 16;
        byte ^= (arow & 7) << 4;
        afrag[k0] = *(const short8*)((const char*)elds + byte);
      }
#pragma unroll
      for (int t2 = 0; t2 < 2; ++t2) {
        f32x4 acc = {0.f, 0.f, 0.f, 0.f};
#pragma unroll
        for (int k0 = 0; k0 < 4; ++k0)
          acc = __builtin_amdgcn_mfma_f32_16x16x32_bf16(afrag[k0], bfrag[t2][k0], acc, 0, 0, 0);
        float bv = bias[r * FDIM + wave * 32 + t2 * 16 + (lane & 15)];
#pragma unroll
        for (int j2 = 0; j2 < 4; ++j2) {
          float nr = nrm_lds[tr * 16 + (lane >> 4) * 4 + j2];
          float v = acc[j2] * nr + bv;
          if (do_relu) v = fmaxf(v, 0.f);
          tot[tr][t2][j2] += v;
        }
      }
    }
  }

  // write hout: elem (row = tr*16+(lane>>4)*4+j2, col = wave*32+t2*16+(lane&15))
#pragma unroll
  for (int tr = 0; tr < 4; ++tr)
#pragma unroll
    for (int t2 = 0; t2 < 2; ++t2)
#pragma unroll
      for (int j2 = 0; j2 < 4; ++j2) {
        int n = base + tr * 16 + (lane >> 4) * 4 + j2;
        if (n < N_NODES)
          hout[(size_t)n * FDIM + wave * 32 + t2 * 16 + (lane & 15)] = f2bf(tot[tr][t2][j2]);
      }
}

// ---------- edge scoring via MFMA (bf16 h), pos+neg in one dispatch ----------
__global__ __launch_bounds__(256) void edge_mfma_kernel(
    const ushort* __restrict__ hb,
    const int* __restrict__ psrc, const int* __restrict__ pdst,
    const int* __restrict__ nsrc, const int* __restrict__ ndst,
    const ushort* __restrict__ bT, const float* __restrict__ P1b,
    const float* __restrict__ P2w, const float* __restrict__ P2b,
    float* __restrict__ out) {
  __shared__ __align__(16) short elds[64 * 128];   // bf16 E tile, XOR-swizzled
  __shared__ float partials[4][64];

  int tid  = threadIdx.x;
  int wave = tid >> 6, lane = tid & 63;
  int b = blockIdx.x;
  const int *esrc, *edst;
  float* o;
  int base;
  if (b < (N_REL * N_EDGES) / 64) {
    esrc = psrc; edst = pdst; o = out; base = b * 64;
  } else {
    esrc = nsrc; edst = ndst; o = out + (size_t)N_REL * N_EDGES;
    base = (b - (N_REL * N_EDGES) / 64) * 64;
  }

  int c0 = (2 * wave) * 16 + (lane & 15);
  int c1 = c0 + 16;
  float bz0 = P1b[c0], bz1 = P1b[c1];
  float wd0 = P2w[c0 * 2 + 1] - P2w[c0 * 2];
  float wd1 = P2w[c1 * 2 + 1] - P2w[c1 * 2];
  float cdiff = P2b[1] - P2b[0];

  short8 bfrag[2][4];
#pragma unroll
  for (int t2 = 0; t2 < 2; ++t2) {
    int c = (2 * wave + t2) * 16 + (lane & 15);
#pragma unroll
    for (int k0 = 0; k0 < 4; ++k0)
      bfrag[t2][k0] = *(const short8*)(bT + (size_t)c * 128 + k0 * 32 + (lane >> 4) * 8);
  }

  // ---- load phase: all 8 row-halves into regs (MLP-8), then convert+store ----
  uint4 av[4], gv[4];
#pragma unroll
  for (int j = 0; j < 4; ++j) {
    int flat = j * 256 + tid;
    int row = flat >> 4, f8 = flat & 15;
    int ge = base + row;
    int s = esrc[ge], d = edst[ge];
    av[j] = *(const uint4*)(hb + (size_t)s * FDIM + f8 * 8);
    gv[j] = *(const uint4*)(hb + (size_t)d * FDIM + f8 * 8);
  }
#pragma unroll
  for (int j = 0; j < 4; ++j) {
    int flat = j * 256 + tid;
    int row = flat >> 4, f8 = flat & 15;
    unsigned w0 = pk2(lo2f(av[j].x) * lo2f(gv[j].x), hi2f(av[j].x) * hi2f(gv[j].x));
    unsigned w1 = pk2(lo2f(av[j].y) * lo2f(gv[j].y), hi2f(av[j].y) * hi2f(gv[j].y));
    unsigned w2 = pk2(lo2f(av[j].z) * lo2f(gv[j].z), hi2f(av[j].z) * hi2f(gv[j].z));
    unsigned w3 = pk2(lo2f(av[j].w) * lo2f(gv[j].w), hi2f(av[j].w) * hi2f(gv[j].w));
    int byte = row * 256 + f8 * 16;
    byte ^= (row & 7) << 4;
    *(uint4*)((char*)elds + byte) = make_uint4(w0, w1, w2, w3);
  }
  __syncthreads();

  float part[4][4];
#pragma unroll
  for (int tr = 0; tr < 4; ++tr)
#pragma unroll
    for (int j2 = 0; j2 < 4; ++j2) part[tr][j2] = 0.f;

#pragma unroll
  for (int tr = 0; tr < 4; ++tr) {
    int arow = tr * 16 + (lane & 15);
    short8 afrag[4];
#pragma unroll
    for (int k0 = 0; k0 < 4; ++k0) {
      int byte = arow * 256 + k0 * 64 + (lane >> 4) * 16;
      byte ^= (arow & 7) << 4;
      afrag[k0] = *(const short8*)((const char*)elds + byte);
    }
#pragma unroll
    for (int t2 = 0; t2 < 2; ++t2) {
      f32x4 acc = {0.f, 0.f, 0.f, 0.f};
#pragma unroll
      for (int k0 = 0; k0 < 4; ++k0)
        acc = __builtin_amdgcn_mfma_f32_16x16x32_bf16(afrag[k0], bfrag[t2][k0], acc, 0, 0, 0);
      float bz = t2 ? bz1 : bz0;
      float wdv = t2 ? wd1 : wd0;
#pragma unroll
      for (int j2 = 0; j2 < 4; ++j2)
        part[tr][j2] += fmaxf(acc[j2] + bz, 0.f) * wdv;
    }
  }

#pragma unroll
  for (int tr = 0; tr < 4; ++tr)
#pragma unroll
    for (int j2 = 0; j2 < 4; ++j2) {
      float v = part[tr][j2];
      v += __shfl_xor(v, 1);
      v += __shfl_xor(v, 2);
      v += __shfl_xor(v, 4);
      v += __shfl_xor(v, 8);
      if ((lane & 15) == 0) partials[wave][tr * 16 + (lane >> 4) * 4 + j2] = v;
    }
  __syncthreads();

  if (tid < 64) {
    float s2 = partials[0][tid] + partials[1][tid] + partials[2][tid] + partials[3][tid] + cdiff;
    o[base + tid] = 1.f / (1.f + expf(-s2));
  }
}

extern "C" void kernel_launch(void* const* d_in, const int* in_sizes, int n_in,
                              void* d_out, int out_size, void* d_ws, size_t ws_size,
                              hipStream_t stream) {
  const float* x   = (const float*)d_in[0];
  const float* W1  = (const float*)d_in[1];
  const float* b1  = (const float*)d_in[2];
  const float* W2  = (const float*)d_in[3];
  const float* b2  = (const float*)d_in[4];
  const float* P1w = (const float*)d_in[5];
  const float* P1b = (const float*)d_in[6];
  const float* P2w = (const float*)d_in[7];
  const float* P2b = (const float*)d_in[8];
  const int* src     = (const int*)d_in[9];
  const int* dst     = (const int*)d_in[10];
  const int* pos_src = (const int*)d_in[11];
  const int* pos_dst = (const int*)d_in[12];
  const int* neg_src = (const int*)d_in[13];
  const int* neg_dst = (const int*)d_in[14];
  float* out = (float*)d_out;

  char* ws = (char*)d_ws;
  int*    cnt    = (int*)ws;     ws += (size_t)N_REL * N_NODES * 4;
  int*    rowp   = (int*)ws;     ws += (size_t)N_REL * N_NODES * 4;
  int*    cursor = (int*)ws;     ws += (size_t)N_REL * N_NODES * 4;
  int*    csr_s  = (int*)ws;     ws += (size_t)N_REL * N_EDGES * 4;
  float*  nrm    = (float*)ws;   ws += (size_t)N_REL * N_NODES * 4;
  ushort* bT     = (ushort*)ws;  ws += (size_t)FDIM * FDIM * 2;
  ushort* wT1    = (ushort*)ws;  ws += (size_t)N_REL * FDIM * FDIM * 2;
  ushort* wT2    = (ushort*)ws;  ws += (size_t)N_REL * FDIM * FDIM * 2;
  ushort* xb     = (ushort*)ws;  ws += (size_t)N_NODES * FDIM * 2;
  ushort* h1b    = (ushort*)ws;  ws += (size_t)N_NODES * FDIM * 2;
  ushort* h2b    = (ushort*)ws;

  // ---- CSR build (shared by both layers) + merged prep ----
  hipMemsetAsync(cnt, 0, (size_t)N_REL * N_NODES * 4, stream);
  cnt_kernel<<<(N_REL * N_EDGES + 255) / 256, 256, 0, stream>>>(dst, cnt);
  scan_kernel<<<N_REL, 1024, 0, stream>>>(cnt, rowp, cursor, nrm);
  fill_kernel<<<(N_REL * N_EDGES + 255) / 256, 256, 0, stream>>>(src, dst, cursor, csr_s);
  {
    int total = N_NODES * FDIM / 4 + FDIM * FDIM + 2 * N_REL * FDIM * FDIM;
    prep_all_kernel<<<(total + 255) / 256, 256, 0, stream>>>(x, xb, P1w, bT, W1, wT1, W2, wT2);
  }

  // ---- layer 1 / layer 2 ----
  conv_mfma_kernel<<<(N_NODES + 63) / 64, 256, 0, stream>>>(
      xb, rowp, cnt, nrm, csr_s, wT1, b1, h1b, 1);
  conv_mfma_kernel<<<(N_NODES + 63) / 64, 256, 0, stream>>>(
      h1b, rowp, cnt, nrm, csr_s, wT2, b2, h2b, 0);

  // ---- edge scores: pos blocks then neg blocks in one dispatch ----
  edge_mfma_kernel<<<2 * (N_REL * N_EDGES) / 64, 256, 0, stream>>>(
      h2b, pos_src, pos_dst, neg_src, neg_dst, bT, P1b, P2w, P2b, out);
}

// Round 8
// 492.260 us; speedup vs baseline: 1.4472x; 1.4472x over previous
//
#include <hip/hip_runtime.h>
#include <hip/hip_bf16.h>
#include <math.h>

#define N_NODES 50000
#define N_EDGES 200000
#define N_REL   4
#define FDIM    128
#define SCAN_BLKS 49   // ceil(50000/1024)

typedef __attribute__((ext_vector_type(8))) short short8;
typedef __attribute__((ext_vector_type(4))) float f32x4;

static __device__ __forceinline__ ushort f2bf(float f) {
  union { float f; unsigned u; } v; v.f = f;
  unsigned r = v.u + 0x7fff + ((v.u >> 16) & 1);   // RNE
  return (ushort)(r >> 16);
}
static __device__ __forceinline__ unsigned pk2(float lo, float hi) {
  __hip_bfloat162 t = __float22bfloat162_rn(make_float2(lo, hi));
  union { __hip_bfloat162 b; unsigned u; } v; v.b = t;
  return v.u;
}
static __device__ __forceinline__ float lo2f(unsigned u) {
  union { unsigned u; float f; } v; v.u = u << 16; return v.f;
}
static __device__ __forceinline__ float hi2f(unsigned u) {
  union { unsigned u; float f; } v; v.u = u & 0xffff0000u; return v.f;
}

// ---------- CSR build: counts ----------
__global__ void cnt_kernel(const int* __restrict__ dst, int* __restrict__ cnt) {
  int i = blockIdx.x * 256 + threadIdx.x;
  if (i < N_REL * N_EDGES) {
    int r = i / N_EDGES;
    atomicAdd(&cnt[r * N_NODES + dst[i]], 1);
  }
}

// ---------- scan phase A: block-local exclusive scan (+ norm) ----------
__global__ __launch_bounds__(1024) void scanA_kernel(
    const int* __restrict__ cnt, int* __restrict__ rowp,
    float* __restrict__ nrm, int* __restrict__ bsum) {
  int r = blockIdx.y, bx = blockIdx.x, t = threadIdx.x;
  int n = bx * 1024 + t;
  int g = r * N_NODES + n;
  int c = 0;
  if (n < N_NODES) {
    c = cnt[g];
    nrm[g] = c > 0 ? 1.f / (float)c : 0.f;
  }
  __shared__ int ts[1024];
  ts[t] = c;
  __syncthreads();
  for (int off = 1; off < 1024; off <<= 1) {
    int v = 0;
    if (t >= off) v = ts[t - off];
    __syncthreads();
    ts[t] += v;
    __syncthreads();
  }
  if (n < N_NODES) rowp[g] = ts[t] - c;   // exclusive
  if (t == 1023) bsum[r * SCAN_BLKS + bx] = ts[t];
}

// ---------- scan phase B: scan the 4×49 block sums ----------
__global__ void scanB_kernel(int* __restrict__ bsum) {
  int r = threadIdx.x;
  if (r < N_REL) {
    int run = r * N_EDGES;
    for (int b = 0; b < SCAN_BLKS; ++b) {
      int t = bsum[r * SCAN_BLKS + b];
      bsum[r * SCAN_BLKS + b] = run;
      run += t;
    }
  }
}

// ---------- scan phase C: add offsets, produce cursor ----------
__global__ void scanC_kernel(int* __restrict__ rowp, int* __restrict__ cursor,
                             const int* __restrict__ bsum) {
  int i = blockIdx.x * 256 + threadIdx.x;
  if (i < N_REL * N_NODES) {
    int r = i / N_NODES;
    int n = i - r * N_NODES;
    int v = rowp[i] + bsum[r * SCAN_BLKS + (n >> 10)];
    rowp[i] = v;
    cursor[i] = v;
  }
}

// ---------- CSR fill ----------
__global__ void fill_kernel(const int* __restrict__ src, const int* __restrict__ dst,
                            int* __restrict__ cursor, int* __restrict__ csr_s) {
  int i = blockIdx.x * 256 + threadIdx.x;
  if (i < N_REL * N_EDGES) {
    int r = i / N_EDGES;
    int pos = atomicAdd(&cursor[r * N_NODES + dst[i]], 1);
    csr_s[pos] = src[i];
  }
}

// ---------- merged prep: cast x->bf16, P1w^T, W1^T, W2^T ----------
__global__ void prep_all_kernel(const float* __restrict__ x, ushort* __restrict__ xb,
                                const float* __restrict__ P1w, ushort* __restrict__ bT,
                                const float* __restrict__ W1, ushort* __restrict__ wT1,
                                const float* __restrict__ W2, ushort* __restrict__ wT2) {
  const int NC = N_NODES * FDIM / 4;
  int i = blockIdx.x * 256 + threadIdx.x;
  if (i < NC) {
    float4 v = ((const float4*)x)[i];
    ((uint2*)xb)[i] = make_uint2(pk2(v.x, v.y), pk2(v.z, v.w));
    return;
  }
  int i2 = i - NC;
  if (i2 < FDIM * FDIM) {                      // bT[c][k] = P1w[k][c]
    int c = i2 >> 7, k = i2 & 127;
    bT[i2] = f2bf(P1w[k * FDIM + c]);
    return;
  }
  i2 -= FDIM * FDIM;
  if (i2 < N_REL * FDIM * FDIM) {              // wT1[r][c][k] = W1[r][k][c]
    int r = i2 >> 14, c = (i2 >> 7) & 127, k = i2 & 127;
    wT1[i2] = f2bf(W1[(r << 14) + (k << 7) + c]);
    return;
  }
  i2 -= N_REL * FDIM * FDIM;
  if (i2 < N_REL * FDIM * FDIM) {
    int r = i2 >> 14, c = (i2 >> 7) & 127, k = i2 & 127;
    wT2[i2] = f2bf(W2[(r << 14) + (k << 7) + c]);
  }
}

// ---------- conv partial: one (64-node tile, relation) per block ----------
// hpart[r][n] = bf16( maybe_relu( (sum_{e->n} hin[src_e]) @ W_r * nrm_r[n] + b_r ) )
__global__ __launch_bounds__(256) void conv_part_kernel(
    const ushort* __restrict__ hin, const int* __restrict__ rowp,
    const int* __restrict__ cnt, const float* __restrict__ nrm,
    const int* __restrict__ csr_s, const ushort* __restrict__ wT,
    const float* __restrict__ bias, ushort* __restrict__ hpart, int do_relu) {
  __shared__ __align__(16) short elds[64 * 128];   // bf16 agg tile, XOR-swizzled
  __shared__ float nrm_lds[64];
  int tid  = threadIdx.x;
  int wave = tid >> 6, lane = tid & 63;
  int base = blockIdx.x * 64;
  int r    = blockIdx.y;
  int ig = tid >> 4, l16 = tid & 15;   // 16 gather groups × 16 lanes

  if (tid < 64) {
    int n = base + tid;
    nrm_lds[tid] = (n < N_NODES) ? nrm[r * N_NODES + n] : 0.f;
  }

  // gather: group ig owns rows {ig, ig+16, ig+32, ig+48}; MLP-4 edge unroll
  for (int rr = ig; rr < 64; rr += 16) {
    int n = base + rr;
    float a8[8];
#pragma unroll
    for (int q = 0; q < 8; ++q) a8[q] = 0.f;
    if (n < N_NODES) {
      int idx = r * N_NODES + n;
      int beg = rowp[idx], num = cnt[idx];
      int j = 0;
      for (; j + 4 <= num; j += 4) {
        int s0 = csr_s[beg + j], s1 = csr_s[beg + j + 1];
        int s2 = csr_s[beg + j + 2], s3 = csr_s[beg + j + 3];
        uint4 v0 = *(const uint4*)(hin + (size_t)s0 * FDIM + l16 * 8);
        uint4 v1 = *(const uint4*)(hin + (size_t)s1 * FDIM + l16 * 8);
        uint4 v2 = *(const uint4*)(hin + (size_t)s2 * FDIM + l16 * 8);
        uint4 v3 = *(const uint4*)(hin + (size_t)s3 * FDIM + l16 * 8);
        a8[0] += lo2f(v0.x) + lo2f(v1.x) + lo2f(v2.x) + lo2f(v3.x);
        a8[1] += hi2f(v0.x) + hi2f(v1.x) + hi2f(v2.x) + hi2f(v3.x);
        a8[2] += lo2f(v0.y) + lo2f(v1.y) + lo2f(v2.y) + lo2f(v3.y);
        a8[3] += hi2f(v0.y) + hi2f(v1.y) + hi2f(v2.y) + hi2f(v3.y);
        a8[4] += lo2f(v0.z) + lo2f(v1.z) + lo2f(v2.z) + lo2f(v3.z);
        a8[5] += hi2f(v0.z) + hi2f(v1.z) + hi2f(v2.z) + hi2f(v3.z);
        a8[6] += lo2f(v0.w) + lo2f(v1.w) + lo2f(v2.w) + lo2f(v3.w);
        a8[7] += hi2f(v0.w) + hi2f(v1.w) + hi2f(v2.w) + hi2f(v3.w);
      }
      for (; j < num; ++j) {
        int s = csr_s[beg + j];
        uint4 v = *(const uint4*)(hin + (size_t)s * FDIM + l16 * 8);
        a8[0] += lo2f(v.x); a8[1] += hi2f(v.x);
        a8[2] += lo2f(v.y); a8[3] += hi2f(v.y);
        a8[4] += lo2f(v.z); a8[5] += hi2f(v.z);
        a8[6] += lo2f(v.w); a8[7] += hi2f(v.w);
      }
    }
    int byte = rr * 256 + l16 * 16;
    byte ^= (rr & 7) << 4;
    *(uint4*)((char*)elds + byte) =
        make_uint4(pk2(a8[0], a8[1]), pk2(a8[2], a8[3]),
                   pk2(a8[4], a8[5]), pk2(a8[6], a8[7]));
  }
  __syncthreads();

  // B fragments: wT[r][c][k], c = wave*32 + t2*16 + (lane&15)
  short8 bfrag[2][4];
#pragma unroll
  for (int t2 = 0; t2 < 2; ++t2) {
    int c = wave * 32 + t2 * 16 + (lane & 15);
#pragma unroll
    for (int k0 = 0; k0 < 4; ++k0)
      bfrag[t2][k0] = *(const short8*)(wT + ((size_t)r * FDIM + c) * FDIM + k0 * 32 + (lane >> 4) * 8);
  }

  ushort* hp = hpart + (size_t)r * N_NODES * FDIM;
#pragma unroll
  for (int tr = 0; tr < 4; ++tr) {
    int arow = tr * 16 + (lane & 15);
    short8 afrag[4];
#pragma unroll
    for (int k0 = 0; k0 < 4; ++k0) {
      int byte = arow * 256 + k0 * 64 + (lane >> 4) * 16;
      byte ^= (arow & 7) << 4;
      afrag[k0] = *(const short8*)((const char*)elds + byte);
    }
#pragma unroll
    for (int t2 = 0; t2 < 2; ++t2) {
      f32x4 acc = {0.f, 0.f, 0.f, 0.f};
#pragma unroll
      for (int k0 = 0; k0 < 4; ++k0)
        acc = __builtin_amdgcn_mfma_f32_16x16x32_bf16(afrag[k0], bfrag[t2][k0], acc, 0, 0, 0);
      int col = wave * 32 + t2 * 16 + (lane & 15);
      float bv = bias[r * FDIM + col];
#pragma unroll
      for (int j2 = 0; j2 < 4; ++j2) {
        int n = base + tr * 16 + (lane >> 4) * 4 + j2;
        if (n < N_NODES) {
          float nr = nrm_lds[tr * 16 + (lane >> 4) * 4 + j2];
          float v = acc[j2] * nr + bv;
          if (do_relu) v = fmaxf(v, 0.f);
          hp[(size_t)n * FDIM + col] = f2bf(v);
        }
      }
    }
  }
}

// ---------- finalize: h = bf16(sum_r hpart[r]) ----------
__global__ void finalize_kernel(const ushort* __restrict__ hpart, ushort* __restrict__ hout) {
  int i = blockIdx.x * 256 + threadIdx.x;   // uint4 (8 bf16) granularity
  const int NV = N_NODES * FDIM / 8;
  if (i < NV) {
    uint4 a = ((const uint4*)hpart)[i];
    uint4 b = ((const uint4*)(hpart + (size_t)N_NODES * FDIM))[i];
    uint4 c = ((const uint4*)(hpart + (size_t)2 * N_NODES * FDIM))[i];
    uint4 d = ((const uint4*)(hpart + (size_t)3 * N_NODES * FDIM))[i];
    float s0 = lo2f(a.x) + lo2f(b.x) + lo2f(c.x) + lo2f(d.x);
    float s1 = hi2f(a.x) + hi2f(b.x) + hi2f(c.x) + hi2f(d.x);
    float s2 = lo2f(a.y) + lo2f(b.y) + lo2f(c.y) + lo2f(d.y);
    float s3 = hi2f(a.y) + hi2f(b.y) + hi2f(c.y) + hi2f(d.y);
    float s4 = lo2f(a.z) + lo2f(b.z) + lo2f(c.z) + lo2f(d.z);
    float s5 = hi2f(a.z) + hi2f(b.z) + hi2f(c.z) + hi2f(d.z);
    float s6 = lo2f(a.w) + lo2f(b.w) + lo2f(c.w) + lo2f(d.w);
    float s7 = hi2f(a.w) + hi2f(b.w) + hi2f(c.w) + hi2f(d.w);
    ((uint4*)hout)[i] = make_uint4(pk2(s0, s1), pk2(s2, s3), pk2(s4, s5), pk2(s6, s7));
  }
}

// ---------- edge scoring via MFMA (bf16 h), pos+neg in one dispatch ----------
__global__ __launch_bounds__(256) void edge_mfma_kernel(
    const ushort* __restrict__ hb,
    const int* __restrict__ psrc, const int* __restrict__ pdst,
    const int* __restrict__ nsrc, const int* __restrict__ ndst,
    const ushort* __restrict__ bT, const float* __restrict__ P1b,
    const float* __restrict__ P2w, const float* __restrict__ P2b,
    float* __restrict__ out) {
  __shared__ __align__(16) short elds[64 * 128];   // bf16 E tile, XOR-swizzled
  __shared__ float partials[4][64];

  int tid  = threadIdx.x;
  int wave = tid >> 6, lane = tid & 63;
  int b = blockIdx.x;
  const int *esrc, *edst;
  float* o;
  int base;
  if (b < (N_REL * N_EDGES) / 64) {
    esrc = psrc; edst = pdst; o = out; base = b * 64;
  } else {
    esrc = nsrc; edst = ndst; o = out + (size_t)N_REL * N_EDGES;
    base = (b - (N_REL * N_EDGES) / 64) * 64;
  }

  int c0 = (2 * wave) * 16 + (lane & 15);
  int c1 = c0 + 16;
  float bz0 = P1b[c0], bz1 = P1b[c1];
  float wd0 = P2w[c0 * 2 + 1] - P2w[c0 * 2];
  float wd1 = P2w[c1 * 2 + 1] - P2w[c1 * 2];
  float cdiff = P2b[1] - P2b[0];

  short8 bfrag[2][4];
#pragma unroll
  for (int t2 = 0; t2 < 2; ++t2) {
    int c = (2 * wave + t2) * 16 + (lane & 15);
#pragma unroll
    for (int k0 = 0; k0 < 4; ++k0)
      bfrag[t2][k0] = *(const short8*)(bT + (size_t)c * 128 + k0 * 32 + (lane >> 4) * 8);
  }

  uint4 av[4], gv[4];
#pragma unroll
  for (int j = 0; j < 4; ++j) {
    int flat = j * 256 + tid;
    int row = flat >> 4, f8 = flat & 15;
    int ge = base + row;
    int s = esrc[ge], d = edst[ge];
    av[j] = *(const uint4*)(hb + (size_t)s * FDIM + f8 * 8);
    gv[j] = *(const uint4*)(hb + (size_t)d * FDIM + f8 * 8);
  }
#pragma unroll
  for (int j = 0; j < 4; ++j) {
    int flat = j * 256 + tid;
    int row = flat >> 4, f8 = flat & 15;
    unsigned w0 = pk2(lo2f(av[j].x) * lo2f(gv[j].x), hi2f(av[j].x) * hi2f(gv[j].x));
    unsigned w1 = pk2(lo2f(av[j].y) * lo2f(gv[j].y), hi2f(av[j].y) * hi2f(gv[j].y));
    unsigned w2 = pk2(lo2f(av[j].z) * lo2f(gv[j].z), hi2f(av[j].z) * hi2f(gv[j].z));
    unsigned w3 = pk2(lo2f(av[j].w) * lo2f(gv[j].w), hi2f(av[j].w) * hi2f(gv[j].w));
    int byte = row * 256 + f8 * 16;
    byte ^= (row & 7) << 4;
    *(uint4*)((char*)elds + byte) = make_uint4(w0, w1, w2, w3);
  }
  __syncthreads();

  float part[4][4];
#pragma unroll
  for (int tr = 0; tr < 4; ++tr)
#pragma unroll
    for (int j2 = 0; j2 < 4; ++j2) part[tr][j2] = 0.f;

#pragma unroll
  for (int tr = 0; tr < 4; ++tr) {
    int arow = tr * 16 + (lane & 15);
    short8 afrag[4];
#pragma unroll
    for (int k0 = 0; k0 < 4; ++k0) {
      int byte = arow * 256 + k0 * 64 + (lane >> 4) * 16;
      byte ^= (arow & 7) << 4;
      afrag[k0] = *(const short8*)((const char*)elds + byte);
    }
#pragma unroll
    for (int t2 = 0; t2 < 2; ++t2) {
      f32x4 acc = {0.f, 0.f, 0.f, 0.f};
#pragma unroll
      for (int k0 = 0; k0 < 4; ++k0)
        acc = __builtin_amdgcn_mfma_f32_16x16x32_bf16(afrag[k0], bfrag[t2][k0], acc, 0, 0, 0);
      float bz = t2 ? bz1 : bz0;
      float wdv = t2 ? wd1 : wd0;
#pragma unroll
      for (int j2 = 0; j2 < 4; ++j2)
        part[tr][j2] += fmaxf(acc[j2] + bz, 0.f) * wdv;
    }
  }

#pragma unroll
  for (int tr = 0; tr < 4; ++tr)
#pragma unroll
    for (int j2 = 0; j2 < 4; ++j2) {
      float v = part[tr][j2];
      v += __shfl_xor(v, 1);
      v += __shfl_xor(v, 2);
      v += __shfl_xor(v, 4);
      v += __shfl_xor(v, 8);
      if ((lane & 15) == 0) partials[wave][tr * 16 + (lane >> 4) * 4 + j2] = v;
    }
  __syncthreads();

  if (tid < 64) {
    float s2 = partials[0][tid] + partials[1][tid] + partials[2][tid] + partials[3][tid] + cdiff;
    o[base + tid] = 1.f / (1.f + expf(-s2));
  }
}

extern "C" void kernel_launch(void* const* d_in, const int* in_sizes, int n_in,
                              void* d_out, int out_size, void* d_ws, size_t ws_size,
                              hipStream_t stream) {
  const float* x   = (const float*)d_in[0];
  const float* W1  = (const float*)d_in[1];
  const float* b1  = (const float*)d_in[2];
  const float* W2  = (const float*)d_in[3];
  const float* b2  = (const float*)d_in[4];
  const float* P1w = (const float*)d_in[5];
  const float* P1b = (const float*)d_in[6];
  const float* P2w = (const float*)d_in[7];
  const float* P2b = (const float*)d_in[8];
  const int* src     = (const int*)d_in[9];
  const int* dst     = (const int*)d_in[10];
  const int* pos_src = (const int*)d_in[11];
  const int* pos_dst = (const int*)d_in[12];
  const int* neg_src = (const int*)d_in[13];
  const int* neg_dst = (const int*)d_in[14];
  float* out = (float*)d_out;

  char* ws = (char*)d_ws;
  int*    cnt    = (int*)ws;     ws += (size_t)N_REL * N_NODES * 4;
  int*    rowp   = (int*)ws;     ws += (size_t)N_REL * N_NODES * 4;
  int*    cursor = (int*)ws;     ws += (size_t)N_REL * N_NODES * 4;
  int*    csr_s  = (int*)ws;     ws += (size_t)N_REL * N_EDGES * 4;
  float*  nrm    = (float*)ws;   ws += (size_t)N_REL * N_NODES * 4;
  int*    bsum   = (int*)ws;     ws += 4096;
  ushort* bT     = (ushort*)ws;  ws += (size_t)FDIM * FDIM * 2;
  ushort* wT1    = (ushort*)ws;  ws += (size_t)N_REL * FDIM * FDIM * 2;
  ushort* wT2    = (ushort*)ws;  ws += (size_t)N_REL * FDIM * FDIM * 2;
  ushort* xb     = (ushort*)ws;  ws += (size_t)N_NODES * FDIM * 2;
  ushort* h1b    = (ushort*)ws;  ws += (size_t)N_NODES * FDIM * 2;
  ushort* h2b    = (ushort*)ws;  ws += (size_t)N_NODES * FDIM * 2;
  ushort* hacc   = (ushort*)ws;  // 4 × N_NODES×FDIM bf16 partials (51.2 MB)

  // ---- CSR build + prep ----
  hipMemsetAsync(cnt, 0, (size_t)N_REL * N_NODES * 4, stream);
  cnt_kernel<<<(N_REL * N_EDGES + 255) / 256, 256, 0, stream>>>(dst, cnt);
  scanA_kernel<<<dim3(SCAN_BLKS, N_REL), 1024, 0, stream>>>(cnt, rowp, nrm, bsum);
  scanB_kernel<<<1, 64, 0, stream>>>(bsum);
  scanC_kernel<<<(N_REL * N_NODES + 255) / 256, 256, 0, stream>>>(rowp, cursor, bsum);
  fill_kernel<<<(N_REL * N_EDGES + 255) / 256, 256, 0, stream>>>(src, dst, cursor, csr_s);
  {
    int total = N_NODES * FDIM / 4 + FDIM * FDIM + 2 * N_REL * FDIM * FDIM;
    prep_all_kernel<<<(total + 255) / 256, 256, 0, stream>>>(x, xb, P1w, bT, W1, wT1, W2, wT2);
  }

  // ---- layer 1: relation-parallel partials then combine ----
  conv_part_kernel<<<dim3((N_NODES + 63) / 64, N_REL), 256, 0, stream>>>(
      xb, rowp, cnt, nrm, csr_s, wT1, b1, hacc, 1);
  finalize_kernel<<<(N_NODES * FDIM / 8 + 255) / 256, 256, 0, stream>>>(hacc, h1b);
  // ---- layer 2 ----
  conv_part_kernel<<<dim3((N_NODES + 63) / 64, N_REL), 256, 0, stream>>>(
      h1b, rowp, cnt, nrm, csr_s, wT2, b2, hacc, 0);
  finalize_kernel<<<(N_NODES * FDIM / 8 + 255) / 256, 256, 0, stream>>>(hacc, h2b);

  // ---- edge scores: pos blocks then neg blocks in one dispatch ----
  edge_mfma_kernel<<<2 * (N_REL * N_EDGES) / 64, 256, 0, stream>>>(
      h2b, pos_src, pos_dst, neg_src, neg_dst, bT, P1b, P2w, P2b, out);
}

// Round 9
// 464.639 us; speedup vs baseline: 1.5332x; 1.0594x over previous
//
#include <hip/hip_runtime.h>
#include <hip/hip_bf16.h>
#include <math.h>

#define N_NODES 50000
#define N_EDGES 200000
#define N_REL   4
#define FDIM    128
#define SCAN_BLKS 49   // ceil(50000/1024)

typedef __attribute__((ext_vector_type(8))) short short8;
typedef __attribute__((ext_vector_type(4))) float f32x4;

static __device__ __forceinline__ ushort f2bf(float f) {
  union { float f; unsigned u; } v; v.f = f;
  unsigned r = v.u + 0x7fff + ((v.u >> 16) & 1);   // RNE
  return (ushort)(r >> 16);
}
static __device__ __forceinline__ unsigned pk2(float lo, float hi) {
  __hip_bfloat162 t = __float22bfloat162_rn(make_float2(lo, hi));
  union { __hip_bfloat162 b; unsigned u; } v; v.b = t;
  return v.u;
}
static __device__ __forceinline__ float lo2f(unsigned u) {
  union { unsigned u; float f; } v; v.u = u << 16; return v.f;
}
static __device__ __forceinline__ float hi2f(unsigned u) {
  union { unsigned u; float f; } v; v.u = u & 0xffff0000u; return v.f;
}

// ---------- CSR build: counts ----------
__global__ void cnt_kernel(const int* __restrict__ dst, int* __restrict__ cnt) {
  int i = blockIdx.x * 256 + threadIdx.x;
  if (i < N_REL * N_EDGES) {
    int r = i / N_EDGES;
    atomicAdd(&cnt[r * N_NODES + dst[i]], 1);
  }
}

// ---------- scan phase A: block-local exclusive scan (+ norm) ----------
__global__ __launch_bounds__(1024) void scanA_kernel(
    const int* __restrict__ cnt, int* __restrict__ rowp,
    float* __restrict__ nrm, int* __restrict__ bsum) {
  int r = blockIdx.y, bx = blockIdx.x, t = threadIdx.x;
  int n = bx * 1024 + t;
  int g = r * N_NODES + n;
  int c = 0;
  if (n < N_NODES) {
    c = cnt[g];
    nrm[g] = c > 0 ? 1.f / (float)c : 0.f;
  }
  __shared__ int ts[1024];
  ts[t] = c;
  __syncthreads();
  for (int off = 1; off < 1024; off <<= 1) {
    int v = 0;
    if (t >= off) v = ts[t - off];
    __syncthreads();
    ts[t] += v;
    __syncthreads();
  }
  if (n < N_NODES) rowp[g] = ts[t] - c;   // exclusive
  if (t == 1023) bsum[r * SCAN_BLKS + bx] = ts[t];
}

// ---------- scan phase B: scan the 4×49 block sums ----------
__global__ void scanB_kernel(int* __restrict__ bsum) {
  int r = threadIdx.x;
  if (r < N_REL) {
    int run = r * N_EDGES;
    for (int b = 0; b < SCAN_BLKS; ++b) {
      int t = bsum[r * SCAN_BLKS + b];
      bsum[r * SCAN_BLKS + b] = run;
      run += t;
    }
  }
}

// ---------- scan phase C: add offsets, produce cursor ----------
__global__ void scanC_kernel(int* __restrict__ rowp, int* __restrict__ cursor,
                             const int* __restrict__ bsum) {
  int i = blockIdx.x * 256 + threadIdx.x;
  if (i < N_REL * N_NODES) {
    int r = i / N_NODES;
    int n = i - r * N_NODES;
    int v = rowp[i] + bsum[r * SCAN_BLKS + (n >> 10)];
    rowp[i] = v;
    cursor[i] = v;
  }
}

// ---------- CSR fill ----------
__global__ void fill_kernel(const int* __restrict__ src, const int* __restrict__ dst,
                            int* __restrict__ cursor, int* __restrict__ csr_s) {
  int i = blockIdx.x * 256 + threadIdx.x;
  if (i < N_REL * N_EDGES) {
    int r = i / N_EDGES;
    int pos = atomicAdd(&cursor[r * N_NODES + dst[i]], 1);
    csr_s[pos] = src[i];
  }
}

// ---------- merged prep: cast x->bf16, P1w^T, W1^T, W2^T ----------
__global__ void prep_all_kernel(const float* __restrict__ x, ushort* __restrict__ xb,
                                const float* __restrict__ P1w, ushort* __restrict__ bT,
                                const float* __restrict__ W1, ushort* __restrict__ wT1,
                                const float* __restrict__ W2, ushort* __restrict__ wT2) {
  const int NC = N_NODES * FDIM / 4;
  int i = blockIdx.x * 256 + threadIdx.x;
  if (i < NC) {
    float4 v = ((const float4*)x)[i];
    ((uint2*)xb)[i] = make_uint2(pk2(v.x, v.y), pk2(v.z, v.w));
    return;
  }
  int i2 = i - NC;
  if (i2 < FDIM * FDIM) {                      // bT[c][k] = P1w[k][c]
    int c = i2 >> 7, k = i2 & 127;
    bT[i2] = f2bf(P1w[k * FDIM + c]);
    return;
  }
  i2 -= FDIM * FDIM;
  if (i2 < N_REL * FDIM * FDIM) {              // wT1[r][c][k] = W1[r][k][c]
    int r = i2 >> 14, c = (i2 >> 7) & 127, k = i2 & 127;
    wT1[i2] = f2bf(W1[(r << 14) + (k << 7) + c]);
    return;
  }
  i2 -= N_REL * FDIM * FDIM;
  if (i2 < N_REL * FDIM * FDIM) {
    int r = i2 >> 14, c = (i2 >> 7) & 127, k = i2 & 127;
    wT2[i2] = f2bf(W2[(r << 14) + (k << 7) + c]);
  }
}

// ---------- conv partial: one (64-node tile, relation) per block ----------
__global__ __launch_bounds__(256) void conv_part_kernel(
    const ushort* __restrict__ hin, const int* __restrict__ rowp,
    const int* __restrict__ cnt, const float* __restrict__ nrm,
    const int* __restrict__ csr_s, const ushort* __restrict__ wT,
    const float* __restrict__ bias, ushort* __restrict__ hpart, int do_relu) {
  __shared__ __align__(16) short elds[64 * 128];   // bf16 agg tile, XOR-swizzled
  __shared__ float nrm_lds[64];
  int tid  = threadIdx.x;
  int wave = tid >> 6, lane = tid & 63;
  int base = blockIdx.x * 64;
  int r    = blockIdx.y;
  int ig = tid >> 4, l16 = tid & 15;   // 16 gather groups × 16 lanes

  if (tid < 64) {
    int n = base + tid;
    nrm_lds[tid] = (n < N_NODES) ? nrm[r * N_NODES + n] : 0.f;
  }

  for (int rr = ig; rr < 64; rr += 16) {
    int n = base + rr;
    float a8[8];
#pragma unroll
    for (int q = 0; q < 8; ++q) a8[q] = 0.f;
    if (n < N_NODES) {
      int idx = r * N_NODES + n;
      int beg = rowp[idx], num = cnt[idx];
      int j = 0;
      for (; j + 4 <= num; j += 4) {
        int s0 = csr_s[beg + j], s1 = csr_s[beg + j + 1];
        int s2 = csr_s[beg + j + 2], s3 = csr_s[beg + j + 3];
        uint4 v0 = *(const uint4*)(hin + (size_t)s0 * FDIM + l16 * 8);
        uint4 v1 = *(const uint4*)(hin + (size_t)s1 * FDIM + l16 * 8);
        uint4 v2 = *(const uint4*)(hin + (size_t)s2 * FDIM + l16 * 8);
        uint4 v3 = *(const uint4*)(hin + (size_t)s3 * FDIM + l16 * 8);
        a8[0] += lo2f(v0.x) + lo2f(v1.x) + lo2f(v2.x) + lo2f(v3.x);
        a8[1] += hi2f(v0.x) + hi2f(v1.x) + hi2f(v2.x) + hi2f(v3.x);
        a8[2] += lo2f(v0.y) + lo2f(v1.y) + lo2f(v2.y) + lo2f(v3.y);
        a8[3] += hi2f(v0.y) + hi2f(v1.y) + hi2f(v2.y) + hi2f(v3.y);
        a8[4] += lo2f(v0.z) + lo2f(v1.z) + lo2f(v2.z) + lo2f(v3.z);
        a8[5] += hi2f(v0.z) + hi2f(v1.z) + hi2f(v2.z) + hi2f(v3.z);
        a8[6] += lo2f(v0.w) + lo2f(v1.w) + lo2f(v2.w) + lo2f(v3.w);
        a8[7] += hi2f(v0.w) + hi2f(v1.w) + hi2f(v2.w) + hi2f(v3.w);
      }
      for (; j < num; ++j) {
        int s = csr_s[beg + j];
        uint4 v = *(const uint4*)(hin + (size_t)s * FDIM + l16 * 8);
        a8[0] += lo2f(v.x); a8[1] += hi2f(v.x);
        a8[2] += lo2f(v.y); a8[3] += hi2f(v.y);
        a8[4] += lo2f(v.z); a8[5] += hi2f(v.z);
        a8[6] += lo2f(v.w); a8[7] += hi2f(v.w);
      }
    }
    int byte = rr * 256 + l16 * 16;
    byte ^= (rr & 7) << 4;
    *(uint4*)((char*)elds + byte) =
        make_uint4(pk2(a8[0], a8[1]), pk2(a8[2], a8[3]),
                   pk2(a8[4], a8[5]), pk2(a8[6], a8[7]));
  }
  __syncthreads();

  short8 bfrag[2][4];
#pragma unroll
  for (int t2 = 0; t2 < 2; ++t2) {
    int c = wave * 32 + t2 * 16 + (lane & 15);
#pragma unroll
    for (int k0 = 0; k0 < 4; ++k0)
      bfrag[t2][k0] = *(const short8*)(wT + ((size_t)r * FDIM + c) * FDIM + k0 * 32 + (lane >> 4) * 8);
  }

  ushort* hp = hpart + (size_t)r * N_NODES * FDIM;
#pragma unroll
  for (int tr = 0; tr < 4; ++tr) {
    int arow = tr * 16 + (lane & 15);
    short8 afrag[4];
#pragma unroll
    for (int k0 = 0; k0 < 4; ++k0) {
      int byte = arow * 256 + k0 * 64 + (lane >> 4) * 16;
      byte ^= (arow & 7) << 4;
      afrag[k0] = *(const short8*)((const char*)elds + byte);
    }
#pragma unroll
    for (int t2 = 0; t2 < 2; ++t2) {
      f32x4 acc = {0.f, 0.f, 0.f, 0.f};
#pragma unroll
      for (int k0 = 0; k0 < 4; ++k0)
        acc = __builtin_amdgcn_mfma_f32_16x16x32_bf16(afrag[k0], bfrag[t2][k0], acc, 0, 0, 0);
      int col = wave * 32 + t2 * 16 + (lane & 15);
      float bv = bias[r * FDIM + col];
#pragma unroll
      for (int j2 = 0; j2 < 4; ++j2) {
        int n = base + tr * 16 + (lane >> 4) * 4 + j2;
        if (n < N_NODES) {
          float nr = nrm_lds[tr * 16 + (lane >> 4) * 4 + j2];
          float v = acc[j2] * nr + bv;
          if (do_relu) v = fmaxf(v, 0.f);
          hp[(size_t)n * FDIM + col] = f2bf(v);
        }
      }
    }
  }
}

// ---------- finalize: h = bf16(sum_r hpart[r]) ----------
__global__ void finalize_kernel(const ushort* __restrict__ hpart, ushort* __restrict__ hout) {
  int i = blockIdx.x * 256 + threadIdx.x;
  const int NV = N_NODES * FDIM / 8;
  if (i < NV) {
    uint4 a = ((const uint4*)hpart)[i];
    uint4 b = ((const uint4*)(hpart + (size_t)N_NODES * FDIM))[i];
    uint4 c = ((const uint4*)(hpart + (size_t)2 * N_NODES * FDIM))[i];
    uint4 d = ((const uint4*)(hpart + (size_t)3 * N_NODES * FDIM))[i];
    float s0 = lo2f(a.x) + lo2f(b.x) + lo2f(c.x) + lo2f(d.x);
    float s1 = hi2f(a.x) + hi2f(b.x) + hi2f(c.x) + hi2f(d.x);
    float s2 = lo2f(a.y) + lo2f(b.y) + lo2f(c.y) + lo2f(d.y);
    float s3 = hi2f(a.y) + hi2f(b.y) + hi2f(c.y) + hi2f(d.y);
    float s4 = lo2f(a.z) + lo2f(b.z) + lo2f(c.z) + lo2f(d.z);
    float s5 = hi2f(a.z) + hi2f(b.z) + hi2f(c.z) + hi2f(d.z);
    float s6 = lo2f(a.w) + lo2f(b.w) + lo2f(c.w) + lo2f(d.w);
    float s7 = hi2f(a.w) + hi2f(b.w) + hi2f(c.w) + hi2f(d.w);
    ((uint4*)hout)[i] = make_uint4(pk2(s0, s1), pk2(s2, s3), pk2(s4, s5), pk2(s6, s7));
  }
}

// ---------- edge scoring via MFMA: 2-tile pipelined, pos+neg in one dispatch ----------
__global__ __launch_bounds__(256) void edge_mfma_kernel(
    const ushort* __restrict__ hb,
    const int* __restrict__ psrc, const int* __restrict__ pdst,
    const int* __restrict__ nsrc, const int* __restrict__ ndst,
    const ushort* __restrict__ bT, const float* __restrict__ P1b,
    const float* __restrict__ P2w, const float* __restrict__ P2b,
    float* __restrict__ out) {
  __shared__ __align__(16) short elds[64 * 128];   // bf16 E tile, XOR-swizzled
  __shared__ float partials[4][128];

  int tid  = threadIdx.x;
  int wave = tid >> 6, lane = tid & 63;
  int b = blockIdx.x;
  const int HALF = (N_REL * N_EDGES) / 128;   // 6250 blocks per side
  const int *esrc, *edst;
  float* o;
  int base;
  if (b < HALF) {
    esrc = psrc; edst = pdst; o = out; base = b * 128;
  } else {
    esrc = nsrc; edst = ndst; o = out + (size_t)N_REL * N_EDGES;
    base = (b - HALF) * 128;
  }

  int c0 = (2 * wave) * 16 + (lane & 15);
  int c1 = c0 + 16;
  float bz0 = P1b[c0], bz1 = P1b[c1];
  float wd0 = P2w[c0 * 2 + 1] - P2w[c0 * 2];
  float wd1 = P2w[c1 * 2 + 1] - P2w[c1 * 2];
  float cdiff = P2b[1] - P2b[0];

  short8 bfrag[2][4];
#pragma unroll
  for (int t2 = 0; t2 < 2; ++t2) {
    int c = (2 * wave + t2) * 16 + (lane & 15);
#pragma unroll
    for (int k0 = 0; k0 < 4; ++k0)
      bfrag[t2][k0] = *(const short8*)(bT + (size_t)c * 128 + k0 * 32 + (lane >> 4) * 8);
  }

  // ---- issue ALL gather loads for both 64-edge tiles up front (T14) ----
  uint4 av0[4], gv0[4], av1[4], gv1[4];
#pragma unroll
  for (int j = 0; j < 4; ++j) {
    int flat = j * 256 + tid;
    int row = flat >> 4, f8 = flat & 15;
    int ge = base + row;
    int s = esrc[ge], d = edst[ge];
    av0[j] = *(const uint4*)(hb + (size_t)s * FDIM + f8 * 8);
    gv0[j] = *(const uint4*)(hb + (size_t)d * FDIM + f8 * 8);
  }
#pragma unroll
  for (int j = 0; j < 4; ++j) {
    int flat = j * 256 + tid;
    int row = flat >> 4, f8 = flat & 15;
    int ge = base + 64 + row;
    int s = esrc[ge], d = edst[ge];
    av1[j] = *(const uint4*)(hb + (size_t)s * FDIM + f8 * 8);
    gv1[j] = *(const uint4*)(hb + (size_t)d * FDIM + f8 * 8);
  }

  float part0[4][4], part1[4][4];
#pragma unroll
  for (int tr = 0; tr < 4; ++tr)
#pragma unroll
    for (int j2 = 0; j2 < 4; ++j2) { part0[tr][j2] = 0.f; part1[tr][j2] = 0.f; }

  // ---- tile 0: convert+store (waits only tile-0 loads), MFMA while tile-1 in flight ----
#pragma unroll
  for (int j = 0; j < 4; ++j) {
    int flat = j * 256 + tid;
    int row = flat >> 4, f8 = flat & 15;
    unsigned w0 = pk2(lo2f(av0[j].x) * lo2f(gv0[j].x), hi2f(av0[j].x) * hi2f(gv0[j].x));
    unsigned w1 = pk2(lo2f(av0[j].y) * lo2f(gv0[j].y), hi2f(av0[j].y) * hi2f(gv0[j].y));
    unsigned w2 = pk2(lo2f(av0[j].z) * lo2f(gv0[j].z), hi2f(av0[j].z) * hi2f(gv0[j].z));
    unsigned w3 = pk2(lo2f(av0[j].w) * lo2f(gv0[j].w), hi2f(av0[j].w) * hi2f(gv0[j].w));
    int byte = row * 256 + f8 * 16;
    byte ^= (row & 7) << 4;
    *(uint4*)((char*)elds + byte) = make_uint4(w0, w1, w2, w3);
  }
  __syncthreads();

#pragma unroll
  for (int tr = 0; tr < 4; ++tr) {
    int arow = tr * 16 + (lane & 15);
    short8 afrag[4];
#pragma unroll
    for (int k0 = 0; k0 < 4; ++k0) {
      int byte = arow * 256 + k0 * 64 + (lane >> 4) * 16;
      byte ^= (arow & 7) << 4;
      afrag[k0] = *(const short8*)((const char*)elds + byte);
    }
#pragma unroll
    for (int t2 = 0; t2 < 2; ++t2) {
      f32x4 acc = {0.f, 0.f, 0.f, 0.f};
#pragma unroll
      for (int k0 = 0; k0 < 4; ++k0)
        acc = __builtin_amdgcn_mfma_f32_16x16x32_bf16(afrag[k0], bfrag[t2][k0], acc, 0, 0, 0);
      float bz = t2 ? bz1 : bz0;
      float wdv = t2 ? wd1 : wd0;
#pragma unroll
      for (int j2 = 0; j2 < 4; ++j2)
        part0[tr][j2] += fmaxf(acc[j2] + bz, 0.f) * wdv;
    }
  }
  __syncthreads();   // all elds reads done before overwrite

  // ---- tile 1 ----
#pragma unroll
  for (int j = 0; j < 4; ++j) {
    int flat = j * 256 + tid;
    int row = flat >> 4, f8 = flat & 15;
    unsigned w0 = pk2(lo2f(av1[j].x) * lo2f(gv1[j].x), hi2f(av1[j].x) * hi2f(gv1[j].x));
    unsigned w1 = pk2(lo2f(av1[j].y) * lo2f(gv1[j].y), hi2f(av1[j].y) * hi2f(gv1[j].y));
    unsigned w2 = pk2(lo2f(av1[j].z) * lo2f(gv1[j].z), hi2f(av1[j].z) * hi2f(gv1[j].z));
    unsigned w3 = pk2(lo2f(av1[j].w) * lo2f(gv1[j].w), hi2f(av1[j].w) * hi2f(gv1[j].w));
    int byte = row * 256 + f8 * 16;
    byte ^= (row & 7) << 4;
    *(uint4*)((char*)elds + byte) = make_uint4(w0, w1, w2, w3);
  }
  __syncthreads();

#pragma unroll
  for (int tr = 0; tr < 4; ++tr) {
    int arow = tr * 16 + (lane & 15);
    short8 afrag[4];
#pragma unroll
    for (int k0 = 0; k0 < 4; ++k0) {
      int byte = arow * 256 + k0 * 64 + (lane >> 4) * 16;
      byte ^= (arow & 7) << 4;
      afrag[k0] = *(const short8*)((const char*)elds + byte);
    }
#pragma unroll
    for (int t2 = 0; t2 < 2; ++t2) {
      f32x4 acc = {0.f, 0.f, 0.f, 0.f};
#pragma unroll
      for (int k0 = 0; k0 < 4; ++k0)
        acc = __builtin_amdgcn_mfma_f32_16x16x32_bf16(afrag[k0], bfrag[t2][k0], acc, 0, 0, 0);
      float bz = t2 ? bz1 : bz0;
      float wdv = t2 ? wd1 : wd0;
#pragma unroll
      for (int j2 = 0; j2 < 4; ++j2)
        part1[tr][j2] += fmaxf(acc[j2] + bz, 0.f) * wdv;
    }
  }

  // ---- epilogue: 16-lane reduce for both tiles, then 128 sigmoid writes ----
#pragma unroll
  for (int tr = 0; tr < 4; ++tr)
#pragma unroll
    for (int j2 = 0; j2 < 4; ++j2) {
      float v = part0[tr][j2];
      v += __shfl_xor(v, 1);
      v += __shfl_xor(v, 2);
      v += __shfl_xor(v, 4);
      v += __shfl_xor(v, 8);
      float u = part1[tr][j2];
      u += __shfl_xor(u, 1);
      u += __shfl_xor(u, 2);
      u += __shfl_xor(u, 4);
      u += __shfl_xor(u, 8);
      if ((lane & 15) == 0) {
        int rowi = tr * 16 + (lane >> 4) * 4 + j2;
        partials[wave][rowi] = v;
        partials[wave][64 + rowi] = u;
      }
    }
  __syncthreads();

  if (tid < 128) {
    float s2 = partials[0][tid] + partials[1][tid] + partials[2][tid] + partials[3][tid] + cdiff;
    o[base + tid] = 1.f / (1.f + expf(-s2));
  }
}

extern "C" void kernel_launch(void* const* d_in, const int* in_sizes, int n_in,
                              void* d_out, int out_size, void* d_ws, size_t ws_size,
                              hipStream_t stream) {
  const float* x   = (const float*)d_in[0];
  const float* W1  = (const float*)d_in[1];
  const float* b1  = (const float*)d_in[2];
  const float* W2  = (const float*)d_in[3];
  const float* b2  = (const float*)d_in[4];
  const float* P1w = (const float*)d_in[5];
  const float* P1b = (const float*)d_in[6];
  const float* P2w = (const float*)d_in[7];
  const float* P2b = (const float*)d_in[8];
  const int* src     = (const int*)d_in[9];
  const int* dst     = (const int*)d_in[10];
  const int* pos_src = (const int*)d_in[11];
  const int* pos_dst = (const int*)d_in[12];
  const int* neg_src = (const int*)d_in[13];
  const int* neg_dst = (const int*)d_in[14];
  float* out = (float*)d_out;

  char* ws = (char*)d_ws;
  int*    cnt    = (int*)ws;     ws += (size_t)N_REL * N_NODES * 4;
  int*    rowp   = (int*)ws;     ws += (size_t)N_REL * N_NODES * 4;
  int*    cursor = (int*)ws;     ws += (size_t)N_REL * N_NODES * 4;
  int*    csr_s  = (int*)ws;     ws += (size_t)N_REL * N_EDGES * 4;
  float*  nrm    = (float*)ws;   ws += (size_t)N_REL * N_NODES * 4;
  int*    bsum   = (int*)ws;     ws += 4096;
  ushort* bT     = (ushort*)ws;  ws += (size_t)FDIM * FDIM * 2;
  ushort* wT1    = (ushort*)ws;  ws += (size_t)N_REL * FDIM * FDIM * 2;
  ushort* wT2    = (ushort*)ws;  ws += (size_t)N_REL * FDIM * FDIM * 2;
  ushort* xb     = (ushort*)ws;  ws += (size_t)N_NODES * FDIM * 2;
  ushort* h1b    = (ushort*)ws;  ws += (size_t)N_NODES * FDIM * 2;
  ushort* h2b    = (ushort*)ws;  ws += (size_t)N_NODES * FDIM * 2;
  ushort* hacc   = (ushort*)ws;  // 4 × N_NODES×FDIM bf16 partials (51.2 MB)

  // ---- CSR build + prep ----
  hipMemsetAsync(cnt, 0, (size_t)N_REL * N_NODES * 4, stream);
  cnt_kernel<<<(N_REL * N_EDGES + 255) / 256, 256, 0, stream>>>(dst, cnt);
  scanA_kernel<<<dim3(SCAN_BLKS, N_REL), 1024, 0, stream>>>(cnt, rowp, nrm, bsum);
  scanB_kernel<<<1, 64, 0, stream>>>(bsum);
  scanC_kernel<<<(N_REL * N_NODES + 255) / 256, 256, 0, stream>>>(rowp, cursor, bsum);
  fill_kernel<<<(N_REL * N_EDGES + 255) / 256, 256, 0, stream>>>(src, dst, cursor, csr_s);
  {
    int total = N_NODES * FDIM / 4 + FDIM * FDIM + 2 * N_REL * FDIM * FDIM;
    prep_all_kernel<<<(total + 255) / 256, 256, 0, stream>>>(x, xb, P1w, bT, W1, wT1, W2, wT2);
  }

  // ---- layer 1: relation-parallel partials then combine ----
  conv_part_kernel<<<dim3((N_NODES + 63) / 64, N_REL), 256, 0, stream>>>(
      xb, rowp, cnt, nrm, csr_s, wT1, b1, hacc, 1);
  finalize_kernel<<<(N_NODES * FDIM / 8 + 255) / 256, 256, 0, stream>>>(hacc, h1b);
  // ---- layer 2 ----
  conv_part_kernel<<<dim3((N_NODES + 63) / 64, N_REL), 256, 0, stream>>>(
      h1b, rowp, cnt, nrm, csr_s, wT2, b2, hacc, 0);
  finalize_kernel<<<(N_NODES * FDIM / 8 + 255) / 256, 256, 0, stream>>>(hacc, h2b);

  // ---- edge scores: 2×6250 blocks, 128 edges each ----
  edge_mfma_kernel<<<2 * (N_REL * N_EDGES) / 128, 256, 0, stream>>>(
      h2b, pos_src, pos_dst, neg_src, neg_dst, bT, P1b, P2w, P2b, out);
}